// Round 6
// baseline (133.447 us; speedup 1.0000x reference)
//
#include <hip/hip_runtime.h>
#include <math.h>

#define B_ 2
#define L_ 2048
#define D_ 512
#define H_ 8
#define E_ 64
#define CHUNK 32
#define NCH 64                 // L_/CHUNK
#define DEN_EPS_ 1e-5f
#define LN_EPS_ 1e-5f

typedef __bf16 bf16x8 __attribute__((ext_vector_type(8)));
typedef __bf16 bf16x4 __attribute__((ext_vector_type(4)));
typedef float  f32x4  __attribute__((ext_vector_type(4)));

__device__ __forceinline__ float sigm(float x) { return 1.f / (1.f + expf(-x)); }
__device__ __forceinline__ float elu1(float x) { return x > 0.f ? x + 1.f : expf(x); }

// async global->LDS 16B/lane; LDS dest = wave-uniform base + lane*16
__device__ __forceinline__ void async_cp16(const void* g, void* l) {
    __builtin_amdgcn_global_load_lds(
        (const __attribute__((address_space(1))) void*)g,
        (__attribute__((address_space(3))) void*)l, 16, 0, 0);
}

// BK=32 tiles: 4 chunks of 8 bf16 per row; chunk swizzle kills bank conflicts
#define SWZ4(row, q) ((((q) ^ ((row) & 3)) * 8))

// ---------------------------------------------------------------------------
// Prep: z=0 Wqkv^T (512x1536 -> [1536][512] bf16), z=1 Wout^T, z=2 x -> bf16
// ---------------------------------------------------------------------------
__global__ __launch_bounds__(256) void k_prep(
    const float* __restrict__ W1, __bf16* __restrict__ D1,
    const float* __restrict__ W2, __bf16* __restrict__ D2,
    const float* __restrict__ X,  __bf16* __restrict__ Xb)
{
    const int t = threadIdx.x;
    if (blockIdx.z == 2) {
        int id = ((int)blockIdx.y * 32 + (int)blockIdx.x) * 256 + t;   // 0..65535
#pragma unroll
        for (int it = 0; it < 4; it++) {
            size_t i = (size_t)it * 524288 + (size_t)id * 8;
            float4 a = *(const float4*)&X[i];
            float4 b = *(const float4*)&X[i + 4];
            bf16x8 o;
            o[0] = (__bf16)a.x; o[1] = (__bf16)a.y; o[2] = (__bf16)a.z; o[3] = (__bf16)a.w;
            o[4] = (__bf16)b.x; o[5] = (__bf16)b.y; o[6] = (__bf16)b.z; o[7] = (__bf16)b.w;
            *(bf16x8*)&Xb[i] = o;
        }
        return;
    }
    const float* src; __bf16* dst; int N;
    if (blockIdx.z == 0) { if (blockIdx.x >= 24) return; src = W1; dst = D1; N = 1536; }
    else                 { if (blockIdx.x >= 8)  return; src = W2; dst = D2; N = 512; }
    const int K = 512;

    __shared__ __bf16 tile[64][68];
    const int kb = blockIdx.y * 64, nb = blockIdx.x * 64;
    const int rr = t >> 4, cc4 = (t & 15) * 4;
#pragma unroll
    for (int p = 0; p < 4; p++) {
        int k = rr + p * 16;
        float4 v = *(const float4*)&src[(size_t)(kb + k) * N + nb + cc4];
        tile[k][cc4 + 0] = (__bf16)v.x;
        tile[k][cc4 + 1] = (__bf16)v.y;
        tile[k][cc4 + 2] = (__bf16)v.z;
        tile[k][cc4 + 3] = (__bf16)v.w;
    }
    __syncthreads();
#pragma unroll
    for (int p = 0; p < 4; p++) {
        int n = rr + p * 16;
        bf16x4 o;
        o[0] = tile[cc4 + 0][n];
        o[1] = tile[cc4 + 1][n];
        o[2] = tile[cc4 + 2][n];
        o[3] = tile[cc4 + 3][n];
        *(bf16x4*)&dst[(size_t)(nb + n) * K + kb + cc4] = o;
    }
}

// ---------------------------------------------------------------------------
// MFMA GEMM 1: qkv = Xb @ WqkvT^T + bias; featurize; scatter bf16 Q/K/V.
// 128x128 tile, BK=32, 4 waves 2x2.  global_load_lds staging, swizzled LDS.
// ---------------------------------------------------------------------------
__global__ __launch_bounds__(256) void k_mfma_qkv(
    const __bf16* __restrict__ Ab, const __bf16* __restrict__ Bt,
    const float* __restrict__ bias,
    __bf16* __restrict__ Qb, __bf16* __restrict__ Kb, __bf16* __restrict__ Vb)
{
    __shared__ __bf16 Al[128 * 32];
    __shared__ __bf16 Bl[128 * 32];
    const int t = threadIdx.x;
    const int w = t >> 6, lane = t & 63;
    const int wm = w >> 1, wn = w & 1;
    const int ll = lane & 15, quad = lane >> 4;
    const int m0 = blockIdx.y * 128, n0 = blockIdx.x * 128;

    f32x4 acc[4][4] = {};
    const int sr  = t >> 2;                       // staging row (0..63)
    const int skz = (((t & 3) ^ (sr & 3)) * 8);   // swizzled k-chunk

    __bf16* A0 = &Al[(w * 16) * 32];
    __bf16* A1p = &Al[(64 + w * 16) * 32];
    __bf16* B0 = &Bl[(w * 16) * 32];
    __bf16* B1p = &Bl[(64 + w * 16) * 32];

    for (int k0 = 0; k0 < D_; k0 += 32) {
        async_cp16(&Ab[(size_t)(m0 + sr) * D_ + k0 + skz],      A0);
        async_cp16(&Ab[(size_t)(m0 + 64 + sr) * D_ + k0 + skz], A1p);
        async_cp16(&Bt[(size_t)(n0 + sr) * D_ + k0 + skz],      B0);
        async_cp16(&Bt[(size_t)(n0 + 64 + sr) * D_ + k0 + skz], B1p);
        __syncthreads();
#pragma unroll
        for (int im = 0; im < 4; im++) {
            int ra = wm * 64 + im * 16 + ll;
            bf16x8 a = *(const bf16x8*)&Al[ra * 32 + SWZ4(ra, quad)];
#pragma unroll
            for (int in = 0; in < 4; in++) {
                int rb = wn * 64 + in * 16 + ll;
                bf16x8 b = *(const bf16x8*)&Bl[rb * 32 + SWZ4(rb, quad)];
                acc[im][in] = __builtin_amdgcn_mfma_f32_16x16x32_bf16(a, b, acc[im][in], 0, 0, 0);
            }
        }
        __syncthreads();
    }

    const int sec = n0 >> 9;   // 0:q 1:k 2:v (uniform per block)
    __bf16* base = (sec == 0 ? Qb : (sec == 1 ? Kb : Vb));
#pragma unroll
    for (int im = 0; im < 4; im++) {
#pragma unroll
        for (int in = 0; in < 4; in++) {
            int n = n0 + wn * 64 + in * 16 + ll;
            int d = n & 511, h = d >> 6, e = d & 63;
            float bv = bias[n];
#pragma unroll
            for (int r = 0; r < 4; r++) {
                int m = m0 + wm * 64 + im * 16 + quad * 4 + r;
                int bb = m >> 11, l = m & 2047;
                float v = acc[im][in][r] + bv;
                if (sec == 0)      v = elu1(v) * 0.125f;
                else if (sec == 1) v = elu1(v);
                base[((size_t)((bb * H_ + h) * L_ + l)) * E_ + e] = (__bf16)v;
            }
        }
    }
}

// ---------------------------------------------------------------------------
// Chunk sums (MFMA): per (b,h,n)  Gt_n = V^T K_w  (stored [f][e], bf16),
//                    g_n[e] = sum_i K_w[i][e] (fp32)
// ---------------------------------------------------------------------------
__global__ __launch_bounds__(256) void k_chunk_g(
    const __bf16* __restrict__ Kb, const __bf16* __restrict__ Vb,
    const float* __restrict__ dl,
    __bf16* __restrict__ Gt, float* __restrict__ gn)
{
    __shared__ __bf16 Kwt[64][40];   // [e][i], weighted
    __shared__ __bf16 Vt[64][40];    // [f][i]
    const int t  = threadIdx.x;
    const int bx = blockIdx.x;
    const int n = bx & 63, h = (bx >> 6) & 7, bb = bx >> 9;
    const int bh = bb * H_ + h;
    const float lam = sigm(dl[h]);

    {   // stage transposed
        int i = t & 31, e0 = (t >> 5) * 8;
        size_t src = ((size_t)bh * L_ + n * CHUNK + i) * E_ + e0;
        float wk = powf(lam, (float)(CHUNK - 1 - i));
        bf16x8 k8 = *(const bf16x8*)&Kb[src];
        bf16x8 v8 = *(const bf16x8*)&Vb[src];
#pragma unroll
        for (int q = 0; q < 8; q++) {
            Kwt[e0 + q][i] = (__bf16)((float)k8[q] * wk);
            Vt[e0 + q][i]  = v8[q];
        }
    }
    __syncthreads();

    const int w = t >> 6, lane = t & 63;
    const int wm = w >> 1, wn = w & 1;
    const int ll = lane & 15, quad = lane >> 4;

    // A-operand rows = f (V), B-operand rows = e (Kw)  ->  C[f][e]
    bf16x8 af[2], bf_[2];
#pragma unroll
    for (int a = 0; a < 2; a++) {
        af[a]  = *(const bf16x8*)&Vt[wm * 32 + a * 16 + ll][quad * 8];
        bf_[a] = *(const bf16x8*)&Kwt[wn * 32 + a * 16 + ll][quad * 8];
    }
    f32x4 acc[2][2] = {};
#pragma unroll
    for (int a = 0; a < 2; a++)
#pragma unroll
        for (int b = 0; b < 2; b++)
            acc[a][b] = __builtin_amdgcn_mfma_f32_16x16x32_bf16(af[a], bf_[b], acc[a][b], 0, 0, 0);

    size_t gbase = ((size_t)bh * NCH + n) * 4096;
#pragma unroll
    for (int a = 0; a < 2; a++)
#pragma unroll
        for (int b = 0; b < 2; b++)
#pragma unroll
            for (int r = 0; r < 4; r++) {
                int f = wm * 32 + a * 16 + quad * 4 + r;
                int e = wn * 32 + b * 16 + ll;
                Gt[gbase + (size_t)f * 64 + e] = (__bf16)acc[a][b][r];
            }

    if (t < 64) {
        float ga = 0.f;
#pragma unroll
        for (int k8 = 0; k8 < 4; k8++) {
            bf16x8 kk = *(const bf16x8*)&Kwt[t][k8 * 8];
#pragma unroll
            for (int q = 0; q < 8; q++) ga += (float)kk[q];
        }
        gn[((size_t)bh * NCH + n) * E_ + t] = ga;
    }
}

// ---------------------------------------------------------------------------
// Scan: block (bh,f); lane = e.  64 independent loads -> in-register scan.
// z-scan via weighted Kogge-Stone.  Emits lam*S^T (bf16) and lam*z (fp32).
// ---------------------------------------------------------------------------
__global__ __launch_bounds__(64) void k_scan_par(
    const __bf16* __restrict__ Gt, const float* __restrict__ gn,
    const float* __restrict__ dl,
    __bf16* __restrict__ Sb, float* __restrict__ zl)
{
    const int lane = threadIdx.x;
    const int bh = blockIdx.x >> 6;
    const int j  = blockIdx.x & 63;          // f for S-scan, e for z-scan
    const float lam = sigm(dl[bh & 7]);
    const float dC  = powf(lam, (float)CHUNK);

    const size_t base = ((size_t)bh * NCH) * 4096 + (size_t)j * 64 + lane;

    __bf16 g[NCH];
#pragma unroll
    for (int n = 0; n < NCH; n++) g[n] = Gt[base + (size_t)n * 4096];

    float s = 0.f;
#pragma unroll
    for (int n = 0; n < NCH; n++) {
        Sb[base + (size_t)n * 4096] = (__bf16)(lam * s);
        s = fmaf(dC, s, (float)g[n]);
    }

    // z-scan: lane = n
    float gv = gn[((size_t)bh * NCH + lane) * E_ + j];
    float wf = dC;
#pragma unroll
    for (int k = 1; k < 64; k <<= 1) {
        float up = __shfl_up(gv, k);
        if (lane >= k) gv = fmaf(wf, up, gv);
        wf = wf * wf;
    }
    float zex = __shfl_up(gv, 1);
    if (lane == 0) zex = 0.f;
    zl[((size_t)bh * NCH + lane) * E_ + j] = lam * zex;
}

// ---------------------------------------------------------------------------
// Attention (MFMA): per (b,h,n):
//   A = Qw Kw^T (masked);  O = A V + Qw S^T;  den = rowsum(A) + Qw.zz + eps
//   S fragments loaded DIRECTLY from global (L2); Qw/Kw swizzled in LDS.
// ---------------------------------------------------------------------------
__global__ __launch_bounds__(256) void k_attn(
    const __bf16* __restrict__ Qb, const __bf16* __restrict__ Kb,
    const __bf16* __restrict__ Vb,
    const __bf16* __restrict__ Sb, const float* __restrict__ zl,
    const float* __restrict__ dl, __bf16* __restrict__ Out)
{
    __shared__ __bf16 Qw[32][64];   // chunk-swizzled
    __shared__ __bf16 Kw[32][64];   // chunk-swizzled
    __shared__ __bf16 Vt[64][40];
    __shared__ __bf16 A1[32][40];
    __shared__ float  den[32];
    __shared__ float  zz[64];

    const int t  = threadIdx.x;
    const int bx = blockIdx.x;
    const int n = bx & 63, h = (bx >> 6) & 7, bb = bx >> 9;
    const int bh = bb * H_ + h;
    const float lam = sigm(dl[h]);

    const int w = t >> 6, lane = t & 63;
    const int ll = lane & 15, quad = lane >> 4;
    const int fw = w * 16;
    const size_t sbase = ((size_t)bh * NCH + n) * 4096;

    // S B-fragments straight from global (issued first to hide L2 latency)
    bf16x8 bS0 = *(const bf16x8*)&Sb[sbase + (size_t)(fw + ll) * 64 + quad * 8];
    bf16x8 bS1 = *(const bf16x8*)&Sb[sbase + (size_t)(fw + ll) * 64 + 32 + quad * 8];

    {   // stage Q,K (weighted, swizzled), V (transposed)
        int i = t >> 3, e0c = t & 7;
        size_t src = ((size_t)bh * L_ + n * CHUNK + i) * E_ + e0c * 8;
        float wq = powf(lam, (float)i);
        float wk = powf(lam, -(float)i);
        bf16x8 q8 = *(const bf16x8*)&Qb[src];
        bf16x8 k8 = *(const bf16x8*)&Kb[src];
        bf16x8 v8 = *(const bf16x8*)&Vb[src];
        bf16x8 qo, ko;
        int e0 = e0c * 8;
#pragma unroll
        for (int q = 0; q < 8; q++) {
            qo[q] = (__bf16)((float)q8[q] * wq);
            ko[q] = (__bf16)((float)k8[q] * wk);
            Vt[e0 + q][i] = v8[q];
        }
        int cs = (e0c ^ (i & 7)) * 8;
        *(bf16x8*)&Qw[i][cs] = qo;
        *(bf16x8*)&Kw[i][cs] = ko;
        if (t < 64) zz[t] = zl[((size_t)bh * NCH + n) * E_ + t];
    }
    __syncthreads();

    // Phase A: each wave one 16x16 tile of the 32x32 A
    {
        const int wm = w >> 1, wn = w & 1;
        int ra = wm * 16 + ll, rb = wn * 16 + ll;
        f32x4 accA = {};
#pragma unroll
        for (int ks = 0; ks < 2; ks++) {
            bf16x8 a = *(const bf16x8*)&Qw[ra][((ks * 4 + quad) ^ (ra & 7)) * 8];
            bf16x8 b = *(const bf16x8*)&Kw[rb][((ks * 4 + quad) ^ (rb & 7)) * 8];
            accA = __builtin_amdgcn_mfma_f32_16x16x32_bf16(a, b, accA, 0, 0, 0);
        }
        int j = wn * 16 + ll;
#pragma unroll
        for (int r = 0; r < 4; r++) {
            int i = wm * 16 + quad * 4 + r;
            A1[i][j] = (__bf16)(j <= i ? accA[r] : 0.f);
        }
    }
    __syncthreads();

    // den
    if (t < 32) {
        float rs = 0.f;
#pragma unroll
        for (int k8 = 0; k8 < 4; k8++) {
            bf16x8 aa = *(const bf16x8*)&A1[t][k8 * 8];
#pragma unroll
            for (int q = 0; q < 8; q++) rs += (float)aa[q];
        }
        float qz = 0.f;
#pragma unroll
        for (int e8 = 0; e8 < 8; e8++) {
            bf16x8 qq = *(const bf16x8*)&Qw[t][(e8 ^ (t & 7)) * 8];
#pragma unroll
            for (int q = 0; q < 8; q++) qz += (float)qq[q] * zz[(e8 ^ (t & 7)) * 8 + q];
        }
        den[t] = rs + qz + DEN_EPS_;
    }

    // Phase O: wave w owns f-range [fw, fw+16)
    f32x4 acc1[2] = {}, acc2[2] = {};
    {
        bf16x8 bV = *(const bf16x8*)&Vt[fw + ll][quad * 8];
#pragma unroll
        for (int im = 0; im < 2; im++) {
            bf16x8 aA = *(const bf16x8*)&A1[im * 16 + ll][quad * 8];
            acc1[im] = __builtin_amdgcn_mfma_f32_16x16x32_bf16(aA, bV, acc1[im], 0, 0, 0);
        }
#pragma unroll
        for (int im = 0; im < 2; im++) {
            int ra = im * 16 + ll;
            bf16x8 aQ0 = *(const bf16x8*)&Qw[ra][((quad) ^ (ra & 7)) * 8];
            bf16x8 aQ1 = *(const bf16x8*)&Qw[ra][((4 + quad) ^ (ra & 7)) * 8];
            acc2[im] = __builtin_amdgcn_mfma_f32_16x16x32_bf16(aQ0, bS0, acc2[im], 0, 0, 0);
            acc2[im] = __builtin_amdgcn_mfma_f32_16x16x32_bf16(aQ1, bS1, acc2[im], 0, 0, 0);
        }
    }
    __syncthreads();

#pragma unroll
    for (int im = 0; im < 2; im++)
#pragma unroll
        for (int r = 0; r < 4; r++) {
            int i = im * 16 + quad * 4 + r;
            float o = (acc1[im][r] + acc2[im][r]) / den[i];
            Out[((size_t)bb * L_ + n * CHUNK + i) * D_ + h * E_ + fw + ll] = (__bf16)o;
        }
}

// ---------------------------------------------------------------------------
// MFMA GEMM 2 + fused LayerNorm: Y = LN(Ao @ WoutT^T + bout)
// 32x512 tile; global_load_lds staging, swizzled LDS.
// ---------------------------------------------------------------------------
__global__ __launch_bounds__(256) void k_mfma_out_ln(
    const __bf16* __restrict__ Ab, const __bf16* __restrict__ Bt,
    const float* __restrict__ bias, const float* __restrict__ gam,
    const float* __restrict__ bet, float* __restrict__ Y)
{
    __shared__ __bf16 Al[32 * 32];
    __shared__ __bf16 Bl[512 * 32];
    __shared__ float gaml[512], betl[512], bl[512];
    __shared__ float redS[4][32], redQ[4][32];
    __shared__ float mv[32][2];

    const int t = threadIdx.x;
    const int w = t >> 6, lane = t & 63;
    const int ll = lane & 15, quad = lane >> 4;
    const int m0 = blockIdx.x * 32;

    {   // preload per-column params
        float2 g = *(const float2*)&gam[t * 2];
        float2 b2 = *(const float2*)&bet[t * 2];
        float2 bo = *(const float2*)&bias[t * 2];
        gaml[t * 2] = g.x;  gaml[t * 2 + 1] = g.y;
        betl[t * 2] = b2.x; betl[t * 2 + 1] = b2.y;
        bl[t * 2]   = bo.x; bl[t * 2 + 1]   = bo.y;
    }

    f32x4 acc[2][8] = {};
    const int sr  = t >> 2;
    const int skz = (((t & 3) ^ (sr & 3)) * 8);
    __bf16* Ald = &Al[(w * 16) * 32];

    for (int k0 = 0; k0 < D_; k0 += 32) {
        if (t < 128)
            async_cp16(&Ab[(size_t)(m0 + sr) * D_ + k0 + skz], Ald);
#pragma unroll
        for (int p = 0; p < 8; p++)
            async_cp16(&Bt[(size_t)(p * 64 + sr) * D_ + k0 + skz], &Bl[(p * 64 + w * 16) * 32]);
        __syncthreads();
#pragma unroll
        for (int im = 0; im < 2; im++) {
            int ra = im * 16 + ll;
            bf16x8 a = *(const bf16x8*)&Al[ra * 32 + SWZ4(ra, quad)];
#pragma unroll
            for (int in = 0; in < 8; in++) {
                int rb = w * 128 + in * 16 + ll;
                bf16x8 b = *(const bf16x8*)&Bl[rb * 32 + SWZ4(rb, quad)];
                acc[im][in] = __builtin_amdgcn_mfma_f32_16x16x32_bf16(a, b, acc[im][in], 0, 0, 0);
            }
        }
        __syncthreads();
    }

    // bias + row-stat partials from registers
    float vals[2][8][4];
    float ps[2][4] = {}, pq[2][4] = {};
#pragma unroll
    for (int im = 0; im < 2; im++)
#pragma unroll
        for (int in = 0; in < 8; in++) {
            int col = w * 128 + in * 16 + ll;
            float bv = bl[col];
#pragma unroll
            for (int r = 0; r < 4; r++) {
                float v = acc[im][in][r] + bv;
                vals[im][in][r] = v;
                ps[im][r] += v;
                pq[im][r] += v * v;
            }
        }
#pragma unroll
    for (int im = 0; im < 2; im++)
#pragma unroll
        for (int r = 0; r < 4; r++) {
            float s = ps[im][r], q = pq[im][r];
            s += __shfl_xor(s, 1); q += __shfl_xor(q, 1);
            s += __shfl_xor(s, 2); q += __shfl_xor(q, 2);
            s += __shfl_xor(s, 4); q += __shfl_xor(q, 4);
            s += __shfl_xor(s, 8); q += __shfl_xor(q, 8);
            if (ll == 0) {
                int row = im * 16 + quad * 4 + r;
                redS[w][row] = s;
                redQ[w][row] = q;
            }
        }
    __syncthreads();
    if (t < 32) {
        float S = redS[0][t] + redS[1][t] + redS[2][t] + redS[3][t];
        float Q = redQ[0][t] + redQ[1][t] + redQ[2][t] + redQ[3][t];
        float mu  = S * (1.f / 512.f);
        float var = Q * (1.f / 512.f) - mu * mu;
        mv[t][0] = mu;
        mv[t][1] = rsqrtf(var + LN_EPS_);
    }
    __syncthreads();
#pragma unroll
    for (int im = 0; im < 2; im++)
#pragma unroll
        for (int r = 0; r < 4; r++) {
            int row = im * 16 + quad * 4 + r;
            float mu = mv[row][0], rs = mv[row][1];
#pragma unroll
            for (int in = 0; in < 8; in++) {
                int col = w * 128 + in * 16 + ll;
                Y[(size_t)(m0 + row) * D_ + col] =
                    (vals[im][in][r] - mu) * rs * gaml[col] + betl[col];
            }
        }
}

// ---------------------------------------------------------------------------
extern "C" void kernel_launch(void* const* d_in, const int* in_sizes, int n_in,
                              void* d_out, int out_size, void* d_ws, size_t ws_size,
                              hipStream_t stream)
{
    const float* x    = (const float*)d_in[0];
    const float* Wqkv = (const float*)d_in[1];
    const float* bqkv = (const float*)d_in[2];
    const float* Wout = (const float*)d_in[3];
    const float* bout = (const float*)d_in[4];
    const float* gam  = (const float*)d_in[5];
    const float* bet  = (const float*)d_in[6];
    const float* dl   = (const float*)d_in[7];
    float* out = (float*)d_out;

    const size_t NBHLE = (size_t)B_ * H_ * L_ * E_;       // 2,097,152
    const size_t NG    = (size_t)B_ * H_ * NCH * E_ * E_; // 4,194,304
    const size_t Ng    = (size_t)B_ * H_ * NCH * E_;      // 65,536

    char* p = (char*)d_ws;
    __bf16* Gt  = (__bf16*)p;    p += NG * 2;
    __bf16* Sb  = (__bf16*)p;    p += NG * 2;
    float*  gn  = (float*)p;     p += Ng * 4;
    float*  zl  = (float*)p;     p += Ng * 4;
    __bf16* Qb  = (__bf16*)p;    p += NBHLE * 2;
    __bf16* Kb  = (__bf16*)p;    p += NBHLE * 2;
    __bf16* Vb  = (__bf16*)p;    p += NBHLE * 2;
    __bf16* Xb    = (__bf16*)p;  p += NBHLE * 2;               // [4096][512]
    __bf16* WqkvT = (__bf16*)p;  p += (size_t)1536 * 512 * 2;
    __bf16* WoutT = (__bf16*)p;  p += (size_t)512 * 512 * 2;
    __bf16* Ao    = (__bf16*)p;  p += NBHLE * 2;               // [4096][512]

    dim3 blk(256);
    k_prep        <<<dim3(32, 8, 3), blk, 0, stream>>>(Wqkv, WqkvT, Wout, WoutT, x, Xb);
    k_mfma_qkv    <<<dim3(12, 32),   blk, 0, stream>>>(Xb, WqkvT, bqkv, Qb, Kb, Vb);
    k_chunk_g     <<<dim3(1024),     blk, 0, stream>>>(Kb, Vb, dl, Gt, gn);
    k_scan_par    <<<dim3(1024),     dim3(64), 0, stream>>>(Gt, gn, dl, Sb, zl);
    k_attn        <<<dim3(1024),     blk, 0, stream>>>(Qb, Kb, Vb, Sb, zl, dl, Ao);
    k_mfma_out_ln <<<dim3(128),      blk, 0, stream>>>(Ao, WoutT, bout, gam, bet, out);
}

// Round 7
// 128.092 us; speedup vs baseline: 1.0418x; 1.0418x over previous
//
#include <hip/hip_runtime.h>
#include <math.h>

#define B_ 2
#define L_ 2048
#define D_ 512
#define H_ 8
#define E_ 64
#define CHUNK 32
#define NCH 64                 // L_/CHUNK
#define DEN_EPS_ 1e-5f
#define LN_EPS_ 1e-5f

typedef __bf16 bf16x8 __attribute__((ext_vector_type(8)));
typedef __bf16 bf16x4 __attribute__((ext_vector_type(4)));
typedef float  f32x4  __attribute__((ext_vector_type(4)));

__device__ __forceinline__ float sigm(float x) { return 1.f / (1.f + expf(-x)); }
__device__ __forceinline__ float elu1(float x) { return x > 0.f ? x + 1.f : expf(x); }

// async global->LDS 16B/lane; LDS dest = wave-uniform base + lane*16
__device__ __forceinline__ void async_cp16(const void* g, void* l) {
    __builtin_amdgcn_global_load_lds(
        (const __attribute__((address_space(1))) void*)g,
        (__attribute__((address_space(3))) void*)l, 16, 0, 0);
}

// BK=32 tiles: 4 chunks of 8 bf16 per row; chunk swizzle kills bank conflicts
#define SWZ4(row, q) ((((q) ^ ((row) & 3)) * 8))

// ---------------------------------------------------------------------------
// Prep: z=0 Wqkv^T (512x1536 -> [1536][512] bf16), z=1 Wout^T, z=2 x -> bf16
// ---------------------------------------------------------------------------
__global__ __launch_bounds__(256) void k_prep(
    const float* __restrict__ W1, __bf16* __restrict__ D1,
    const float* __restrict__ W2, __bf16* __restrict__ D2,
    const float* __restrict__ X,  __bf16* __restrict__ Xb)
{
    const int t = threadIdx.x;
    if (blockIdx.z == 2) {
        int id = ((int)blockIdx.y * 32 + (int)blockIdx.x) * 256 + t;   // 0..65535
#pragma unroll
        for (int it = 0; it < 4; it++) {
            size_t i = (size_t)it * 524288 + (size_t)id * 8;
            float4 a = *(const float4*)&X[i];
            float4 b = *(const float4*)&X[i + 4];
            bf16x8 o;
            o[0] = (__bf16)a.x; o[1] = (__bf16)a.y; o[2] = (__bf16)a.z; o[3] = (__bf16)a.w;
            o[4] = (__bf16)b.x; o[5] = (__bf16)b.y; o[6] = (__bf16)b.z; o[7] = (__bf16)b.w;
            *(bf16x8*)&Xb[i] = o;
        }
        return;
    }
    const float* src; __bf16* dst; int N;
    if (blockIdx.z == 0) { if (blockIdx.x >= 24) return; src = W1; dst = D1; N = 1536; }
    else                 { if (blockIdx.x >= 8)  return; src = W2; dst = D2; N = 512; }
    const int K = 512;

    __shared__ __bf16 tile[64][68];
    const int kb = blockIdx.y * 64, nb = blockIdx.x * 64;
    const int rr = t >> 4, cc4 = (t & 15) * 4;
#pragma unroll
    for (int p = 0; p < 4; p++) {
        int k = rr + p * 16;
        float4 v = *(const float4*)&src[(size_t)(kb + k) * N + nb + cc4];
        tile[k][cc4 + 0] = (__bf16)v.x;
        tile[k][cc4 + 1] = (__bf16)v.y;
        tile[k][cc4 + 2] = (__bf16)v.z;
        tile[k][cc4 + 3] = (__bf16)v.w;
    }
    __syncthreads();
#pragma unroll
    for (int p = 0; p < 4; p++) {
        int n = rr + p * 16;
        bf16x4 o;
        o[0] = tile[cc4 + 0][n];
        o[1] = tile[cc4 + 1][n];
        o[2] = tile[cc4 + 2][n];
        o[3] = tile[cc4 + 3][n];
        *(bf16x4*)&dst[(size_t)(nb + n) * K + kb + cc4] = o;
    }
}

// ---------------------------------------------------------------------------
// MFMA GEMM 1: qkv = Xb @ WqkvT^T + bias; featurize; scatter bf16 Q/K/V.
// 64x128 tile (768 blocks = 3/CU), BK=32, 4 waves 2x2.
// ---------------------------------------------------------------------------
__global__ __launch_bounds__(256) void k_mfma_qkv(
    const __bf16* __restrict__ Ab, const __bf16* __restrict__ Bt,
    const float* __restrict__ bias,
    __bf16* __restrict__ Qb, __bf16* __restrict__ Kb, __bf16* __restrict__ Vb)
{
    __shared__ __bf16 Al[64 * 32];
    __shared__ __bf16 Bl[128 * 32];
    const int t = threadIdx.x;
    const int w = t >> 6, lane = t & 63;
    const int wm = w >> 1, wn = w & 1;
    const int ll = lane & 15, quad = lane >> 4;
    const int m0 = blockIdx.y * 64, n0 = blockIdx.x * 128;

    f32x4 acc[2][4] = {};
    const int sr  = t >> 2;                       // staging row (0..63)
    const int skz = (((t & 3) ^ (sr & 3)) * 8);   // swizzled k-chunk

    __bf16* A0  = &Al[(w * 16) * 32];
    __bf16* B0  = &Bl[(w * 16) * 32];
    __bf16* B1p = &Bl[(64 + w * 16) * 32];

    for (int k0 = 0; k0 < D_; k0 += 32) {
        async_cp16(&Ab[(size_t)(m0 + sr) * D_ + k0 + skz],      A0);
        async_cp16(&Bt[(size_t)(n0 + sr) * D_ + k0 + skz],      B0);
        async_cp16(&Bt[(size_t)(n0 + 64 + sr) * D_ + k0 + skz], B1p);
        __syncthreads();
#pragma unroll
        for (int im = 0; im < 2; im++) {
            int ra = wm * 32 + im * 16 + ll;
            bf16x8 a = *(const bf16x8*)&Al[ra * 32 + SWZ4(ra, quad)];
#pragma unroll
            for (int in = 0; in < 4; in++) {
                int rb = wn * 64 + in * 16 + ll;
                bf16x8 b = *(const bf16x8*)&Bl[rb * 32 + SWZ4(rb, quad)];
                acc[im][in] = __builtin_amdgcn_mfma_f32_16x16x32_bf16(a, b, acc[im][in], 0, 0, 0);
            }
        }
        __syncthreads();
    }

    const int sec = n0 >> 9;   // 0:q 1:k 2:v (uniform per block)
    __bf16* base = (sec == 0 ? Qb : (sec == 1 ? Kb : Vb));
#pragma unroll
    for (int im = 0; im < 2; im++) {
#pragma unroll
        for (int in = 0; in < 4; in++) {
            int n = n0 + wn * 64 + in * 16 + ll;
            int d = n & 511, h = d >> 6, e = d & 63;
            float bv = bias[n];
#pragma unroll
            for (int r = 0; r < 4; r++) {
                int m = m0 + wm * 32 + im * 16 + quad * 4 + r;
                int bb = m >> 11, l = m & 2047;
                float v = acc[im][in][r] + bv;
                if (sec == 0)      v = elu1(v) * 0.125f;
                else if (sec == 1) v = elu1(v);
                base[((size_t)((bb * H_ + h) * L_ + l)) * E_ + e] = (__bf16)v;
            }
        }
    }
}

// ---------------------------------------------------------------------------
// Chunk sums (MFMA): per (b,h,n)  Gt_n = V^T K_w  (stored [f][e], bf16),
//                    g_n[e] = sum_i K_w[i][e] (fp32)
// ---------------------------------------------------------------------------
__global__ __launch_bounds__(256) void k_chunk_g(
    const __bf16* __restrict__ Kb, const __bf16* __restrict__ Vb,
    const float* __restrict__ dl,
    __bf16* __restrict__ Gt, float* __restrict__ gn)
{
    __shared__ __bf16 Kwt[64][40];   // [e][i], weighted
    __shared__ __bf16 Vt[64][40];    // [f][i]
    const int t  = threadIdx.x;
    const int bx = blockIdx.x;
    const int n = bx & 63, h = (bx >> 6) & 7, bb = bx >> 9;
    const int bh = bb * H_ + h;
    const float lam = sigm(dl[h]);

    {   // stage transposed
        int i = t & 31, e0 = (t >> 5) * 8;
        size_t src = ((size_t)bh * L_ + n * CHUNK + i) * E_ + e0;
        float wk = powf(lam, (float)(CHUNK - 1 - i));
        bf16x8 k8 = *(const bf16x8*)&Kb[src];
        bf16x8 v8 = *(const bf16x8*)&Vb[src];
#pragma unroll
        for (int q = 0; q < 8; q++) {
            Kwt[e0 + q][i] = (__bf16)((float)k8[q] * wk);
            Vt[e0 + q][i]  = v8[q];
        }
    }
    __syncthreads();

    const int w = t >> 6, lane = t & 63;
    const int wm = w >> 1, wn = w & 1;
    const int ll = lane & 15, quad = lane >> 4;

    // A-operand rows = f (V), B-operand rows = e (Kw)  ->  C[f][e]
    bf16x8 af[2], bf_[2];
#pragma unroll
    for (int a = 0; a < 2; a++) {
        af[a]  = *(const bf16x8*)&Vt[wm * 32 + a * 16 + ll][quad * 8];
        bf_[a] = *(const bf16x8*)&Kwt[wn * 32 + a * 16 + ll][quad * 8];
    }
    f32x4 acc[2][2] = {};
#pragma unroll
    for (int a = 0; a < 2; a++)
#pragma unroll
        for (int b = 0; b < 2; b++)
            acc[a][b] = __builtin_amdgcn_mfma_f32_16x16x32_bf16(af[a], bf_[b], acc[a][b], 0, 0, 0);

    size_t gbase = ((size_t)bh * NCH + n) * 4096;
#pragma unroll
    for (int a = 0; a < 2; a++)
#pragma unroll
        for (int b = 0; b < 2; b++)
#pragma unroll
            for (int r = 0; r < 4; r++) {
                int f = wm * 32 + a * 16 + quad * 4 + r;
                int e = wn * 32 + b * 16 + ll;
                Gt[gbase + (size_t)f * 64 + e] = (__bf16)acc[a][b][r];
            }

    if (t < 64) {
        float ga = 0.f;
#pragma unroll
        for (int k8 = 0; k8 < 4; k8++) {
            bf16x8 kk = *(const bf16x8*)&Kwt[t][k8 * 8];
#pragma unroll
            for (int q = 0; q < 8; q++) ga += (float)kk[q];
        }
        gn[((size_t)bh * NCH + n) * E_ + t] = ga;
    }
}

// ---------------------------------------------------------------------------
// Scan: block (bh,f); lane = e.  64 independent loads -> in-register scan.
// z-scan via weighted Kogge-Stone.  Emits lam*S^T (bf16) and lam*z (fp32).
// ---------------------------------------------------------------------------
__global__ __launch_bounds__(64) void k_scan_par(
    const __bf16* __restrict__ Gt, const float* __restrict__ gn,
    const float* __restrict__ dl,
    __bf16* __restrict__ Sb, float* __restrict__ zl)
{
    const int lane = threadIdx.x;
    const int bh = blockIdx.x >> 6;
    const int j  = blockIdx.x & 63;          // f for S-scan, e for z-scan
    const float lam = sigm(dl[bh & 7]);
    const float dC  = powf(lam, (float)CHUNK);

    const size_t base = ((size_t)bh * NCH) * 4096 + (size_t)j * 64 + lane;

    __bf16 g[NCH];
#pragma unroll
    for (int n = 0; n < NCH; n++) g[n] = Gt[base + (size_t)n * 4096];

    float s = 0.f;
#pragma unroll
    for (int n = 0; n < NCH; n++) {
        Sb[base + (size_t)n * 4096] = (__bf16)(lam * s);
        s = fmaf(dC, s, (float)g[n]);
    }

    // z-scan: lane = n
    float gv = gn[((size_t)bh * NCH + lane) * E_ + j];
    float wf = dC;
#pragma unroll
    for (int k = 1; k < 64; k <<= 1) {
        float up = __shfl_up(gv, k);
        if (lane >= k) gv = fmaf(wf, up, gv);
        wf = wf * wf;
    }
    float zex = __shfl_up(gv, 1);
    if (lane == 0) zex = 0.f;
    zl[((size_t)bh * NCH + lane) * E_ + j] = lam * zex;
}

// ---------------------------------------------------------------------------
// Attention (MFMA): per (b,h,n):
//   A = Qw Kw^T (masked);  O = A V + Qw S^T;  den = rowsum(A) + Qw.zz + eps
//   S fragments loaded DIRECTLY from global (L2); Qw/Kw swizzled in LDS.
// ---------------------------------------------------------------------------
__global__ __launch_bounds__(256) void k_attn(
    const __bf16* __restrict__ Qb, const __bf16* __restrict__ Kb,
    const __bf16* __restrict__ Vb,
    const __bf16* __restrict__ Sb, const float* __restrict__ zl,
    const float* __restrict__ dl, __bf16* __restrict__ Out)
{
    __shared__ __bf16 Qw[32][64];   // chunk-swizzled
    __shared__ __bf16 Kw[32][64];   // chunk-swizzled
    __shared__ __bf16 Vt[64][40];
    __shared__ __bf16 A1[32][40];
    __shared__ float  den[32];
    __shared__ float  zz[64];

    const int t  = threadIdx.x;
    const int bx = blockIdx.x;
    const int n = bx & 63, h = (bx >> 6) & 7, bb = bx >> 9;
    const int bh = bb * H_ + h;
    const float lam = sigm(dl[h]);

    const int w = t >> 6, lane = t & 63;
    const int ll = lane & 15, quad = lane >> 4;
    const int fw = w * 16;
    const size_t sbase = ((size_t)bh * NCH + n) * 4096;

    // S B-fragments straight from global (issued first to hide L2 latency)
    bf16x8 bS0 = *(const bf16x8*)&Sb[sbase + (size_t)(fw + ll) * 64 + quad * 8];
    bf16x8 bS1 = *(const bf16x8*)&Sb[sbase + (size_t)(fw + ll) * 64 + 32 + quad * 8];

    {   // stage Q,K (weighted, swizzled), V (transposed)
        int i = t >> 3, e0c = t & 7;
        size_t src = ((size_t)bh * L_ + n * CHUNK + i) * E_ + e0c * 8;
        float wq = powf(lam, (float)i);
        float wk = powf(lam, -(float)i);
        bf16x8 q8 = *(const bf16x8*)&Qb[src];
        bf16x8 k8 = *(const bf16x8*)&Kb[src];
        bf16x8 v8 = *(const bf16x8*)&Vb[src];
        bf16x8 qo, ko;
        int e0 = e0c * 8;
#pragma unroll
        for (int q = 0; q < 8; q++) {
            qo[q] = (__bf16)((float)q8[q] * wq);
            ko[q] = (__bf16)((float)k8[q] * wk);
            Vt[e0 + q][i] = v8[q];
        }
        int cs = (e0c ^ (i & 7)) * 8;
        *(bf16x8*)&Qw[i][cs] = qo;
        *(bf16x8*)&Kw[i][cs] = ko;
        if (t < 64) zz[t] = zl[((size_t)bh * NCH + n) * E_ + t];
    }
    __syncthreads();

    // Phase A: each wave one 16x16 tile of the 32x32 A
    {
        const int wm = w >> 1, wn = w & 1;
        int ra = wm * 16 + ll, rb = wn * 16 + ll;
        f32x4 accA = {};
#pragma unroll
        for (int ks = 0; ks < 2; ks++) {
            bf16x8 a = *(const bf16x8*)&Qw[ra][((ks * 4 + quad) ^ (ra & 7)) * 8];
            bf16x8 b = *(const bf16x8*)&Kw[rb][((ks * 4 + quad) ^ (rb & 7)) * 8];
            accA = __builtin_amdgcn_mfma_f32_16x16x32_bf16(a, b, accA, 0, 0, 0);
        }
        int j = wn * 16 + ll;
#pragma unroll
        for (int r = 0; r < 4; r++) {
            int i = wm * 16 + quad * 4 + r;
            A1[i][j] = (__bf16)(j <= i ? accA[r] : 0.f);
        }
    }
    __syncthreads();

    // den  (Qw column chunk (e8 ^ (t&7)) holds e-range e8*8 -> pair with zz[e8*8+q])
    if (t < 32) {
        float rs = 0.f;
#pragma unroll
        for (int k8 = 0; k8 < 4; k8++) {
            bf16x8 aa = *(const bf16x8*)&A1[t][k8 * 8];
#pragma unroll
            for (int q = 0; q < 8; q++) rs += (float)aa[q];
        }
        float qz = 0.f;
#pragma unroll
        for (int e8 = 0; e8 < 8; e8++) {
            bf16x8 qq = *(const bf16x8*)&Qw[t][(e8 ^ (t & 7)) * 8];
#pragma unroll
            for (int q = 0; q < 8; q++) qz += (float)qq[q] * zz[e8 * 8 + q];
        }
        den[t] = rs + qz + DEN_EPS_;
    }

    // Phase O: wave w owns f-range [fw, fw+16)
    f32x4 acc1[2] = {}, acc2[2] = {};
    {
        bf16x8 bV = *(const bf16x8*)&Vt[fw + ll][quad * 8];
#pragma unroll
        for (int im = 0; im < 2; im++) {
            bf16x8 aA = *(const bf16x8*)&A1[im * 16 + ll][quad * 8];
            acc1[im] = __builtin_amdgcn_mfma_f32_16x16x32_bf16(aA, bV, acc1[im], 0, 0, 0);
        }
#pragma unroll
        for (int im = 0; im < 2; im++) {
            int ra = im * 16 + ll;
            bf16x8 aQ0 = *(const bf16x8*)&Qw[ra][((quad) ^ (ra & 7)) * 8];
            bf16x8 aQ1 = *(const bf16x8*)&Qw[ra][((4 + quad) ^ (ra & 7)) * 8];
            acc2[im] = __builtin_amdgcn_mfma_f32_16x16x32_bf16(aQ0, bS0, acc2[im], 0, 0, 0);
            acc2[im] = __builtin_amdgcn_mfma_f32_16x16x32_bf16(aQ1, bS1, acc2[im], 0, 0, 0);
        }
    }
    __syncthreads();

#pragma unroll
    for (int im = 0; im < 2; im++)
#pragma unroll
        for (int r = 0; r < 4; r++) {
            int i = im * 16 + quad * 4 + r;
            float o = (acc1[im][r] + acc2[im][r]) / den[i];
            Out[((size_t)bb * L_ + n * CHUNK + i) * D_ + h * E_ + fw + ll] = (__bf16)o;
        }
}

// ---------------------------------------------------------------------------
// MFMA GEMM 2 + fused LayerNorm: Y = LN(Ao @ WoutT^T + bout)
// 16x512 tile (256 blocks = 1/CU); global_load_lds staging, swizzled LDS.
// ---------------------------------------------------------------------------
__global__ __launch_bounds__(256) void k_mfma_out_ln(
    const __bf16* __restrict__ Ab, const __bf16* __restrict__ Bt,
    const float* __restrict__ bias, const float* __restrict__ gam,
    const float* __restrict__ bet, float* __restrict__ Y)
{
    __shared__ __bf16 Al[16 * 32];
    __shared__ __bf16 Bl[512 * 32];
    __shared__ float gaml[512], betl[512], bl[512];
    __shared__ float redS[4][16], redQ[4][16];
    __shared__ float mv[16][2];

    const int t = threadIdx.x;
    const int w = t >> 6, lane = t & 63;
    const int ll = lane & 15, quad = lane >> 4;
    const int m0 = blockIdx.x * 16;

    {   // preload per-column params
        float2 g = *(const float2*)&gam[t * 2];
        float2 b2 = *(const float2*)&bet[t * 2];
        float2 bo = *(const float2*)&bias[t * 2];
        gaml[t * 2] = g.x;  gaml[t * 2 + 1] = g.y;
        betl[t * 2] = b2.x; betl[t * 2 + 1] = b2.y;
        bl[t * 2]   = bo.x; bl[t * 2 + 1]   = bo.y;
    }

    f32x4 acc[8] = {};
    const int sr  = t >> 2;
    const int skz = (((t & 3) ^ (sr & 3)) * 8);

    for (int k0 = 0; k0 < D_; k0 += 32) {
        if (t < 64)   // 16 rows x 4 chunks = exactly one wave
            async_cp16(&Ab[(size_t)(m0 + sr) * D_ + k0 + skz], &Al[0]);
#pragma unroll
        for (int p = 0; p < 8; p++)
            async_cp16(&Bt[(size_t)(p * 64 + sr) * D_ + k0 + skz], &Bl[(p * 64 + w * 16) * 32]);
        __syncthreads();
        bf16x8 a = *(const bf16x8*)&Al[ll * 32 + SWZ4(ll, quad)];
#pragma unroll
        for (int in = 0; in < 8; in++) {
            int rb = w * 128 + in * 16 + ll;
            bf16x8 b = *(const bf16x8*)&Bl[rb * 32 + SWZ4(rb, quad)];
            acc[in] = __builtin_amdgcn_mfma_f32_16x16x32_bf16(a, b, acc[in], 0, 0, 0);
        }
        __syncthreads();
    }

    // bias + row-stat partials from registers
    float vals[8][4];
    float ps[4] = {}, pq[4] = {};
#pragma unroll
    for (int in = 0; in < 8; in++) {
        int col = w * 128 + in * 16 + ll;
        float bv = bl[col];
#pragma unroll
        for (int r = 0; r < 4; r++) {
            float v = acc[in][r] + bv;
            vals[in][r] = v;
            ps[r] += v;
            pq[r] += v * v;
        }
    }
#pragma unroll
    for (int r = 0; r < 4; r++) {
        float s = ps[r], q = pq[r];
        s += __shfl_xor(s, 1); q += __shfl_xor(q, 1);
        s += __shfl_xor(s, 2); q += __shfl_xor(q, 2);
        s += __shfl_xor(s, 4); q += __shfl_xor(q, 4);
        s += __shfl_xor(s, 8); q += __shfl_xor(q, 8);
        if (ll == 0) {
            int row = quad * 4 + r;
            redS[w][row] = s;
            redQ[w][row] = q;
        }
    }
    __syncthreads();
    if (t < 16) {
        float S = redS[0][t] + redS[1][t] + redS[2][t] + redS[3][t];
        float Q = redQ[0][t] + redQ[1][t] + redQ[2][t] + redQ[3][t];
        float mu  = S * (1.f / 512.f);
        float var = Q * (1.f / 512.f) - mu * mu;
        mv[t][0] = mu;
        mv[t][1] = rsqrtf(var + LN_EPS_);
    }
    __syncthreads();
#pragma unroll
    for (int r = 0; r < 4; r++) {
        int row = quad * 4 + r;
        float mu = mv[row][0], rs = mv[row][1];
#pragma unroll
        for (int in = 0; in < 8; in++) {
            int col = w * 128 + in * 16 + ll;
            Y[(size_t)(m0 + row) * D_ + col] =
                (vals[in][r] - mu) * rs * gaml[col] + betl[col];
        }
    }
}

// ---------------------------------------------------------------------------
extern "C" void kernel_launch(void* const* d_in, const int* in_sizes, int n_in,
                              void* d_out, int out_size, void* d_ws, size_t ws_size,
                              hipStream_t stream)
{
    const float* x    = (const float*)d_in[0];
    const float* Wqkv = (const float*)d_in[1];
    const float* bqkv = (const float*)d_in[2];
    const float* Wout = (const float*)d_in[3];
    const float* bout = (const float*)d_in[4];
    const float* gam  = (const float*)d_in[5];
    const float* bet  = (const float*)d_in[6];
    const float* dl   = (const float*)d_in[7];
    float* out = (float*)d_out;

    const size_t NBHLE = (size_t)B_ * H_ * L_ * E_;       // 2,097,152
    const size_t NG    = (size_t)B_ * H_ * NCH * E_ * E_; // 4,194,304
    const size_t Ng    = (size_t)B_ * H_ * NCH * E_;      // 65,536

    char* p = (char*)d_ws;
    __bf16* Gt  = (__bf16*)p;    p += NG * 2;
    __bf16* Sb  = (__bf16*)p;    p += NG * 2;
    float*  gn  = (float*)p;     p += Ng * 4;
    float*  zl  = (float*)p;     p += Ng * 4;
    __bf16* Qb  = (__bf16*)p;    p += NBHLE * 2;
    __bf16* Kb  = (__bf16*)p;    p += NBHLE * 2;
    __bf16* Vb  = (__bf16*)p;    p += NBHLE * 2;
    __bf16* Xb    = (__bf16*)p;  p += NBHLE * 2;               // [4096][512]
    __bf16* WqkvT = (__bf16*)p;  p += (size_t)1536 * 512 * 2;
    __bf16* WoutT = (__bf16*)p;  p += (size_t)512 * 512 * 2;
    __bf16* Ao    = (__bf16*)p;  p += NBHLE * 2;               // [4096][512]

    dim3 blk(256);
    k_prep        <<<dim3(32, 8, 3), blk, 0, stream>>>(Wqkv, WqkvT, Wout, WoutT, x, Xb);
    k_mfma_qkv    <<<dim3(12, 64),   blk, 0, stream>>>(Xb, WqkvT, bqkv, Qb, Kb, Vb);
    k_chunk_g     <<<dim3(1024),     blk, 0, stream>>>(Kb, Vb, dl, Gt, gn);
    k_scan_par    <<<dim3(1024),     dim3(64), 0, stream>>>(Gt, gn, dl, Sb, zl);
    k_attn        <<<dim3(1024),     blk, 0, stream>>>(Qb, Kb, Vb, Sb, zl, dl, Ao);
    k_mfma_out_ln <<<dim3(256),      blk, 0, stream>>>(Ao, WoutT, bout, gam, bet, out);
}